// Round 8
// baseline (19311.922 us; speedup 1.0000x reference)
//
#include <hip/hip_runtime.h>

// Encoder: 3-layer bidirectional-weights LSTM (both dirs scan forward per the
// reference), H=256, B=64, T=1024, then 256->81 linear + argmax (softmax is
// monotone -> dead code).
//
// R8: weights via the SCALAR pipe. R5/R6b analysis: wave-uniform weight fetch
// through any vector path (L1 vector loads OR ds_read_b128 broadcasts) costs
// ~96+ cyc per k4 vs 64 cyc FMA -> both plateau at 18.4ms. Now: per k4, one
// fused asm block of 8x s_load_dwordx4 (SMEM/lgkm pipe, ~2 cyc issue each)
// into SGPRs; FMAs consume the weight as the single legal SGPR operand
// (v_fmac v, s, v). No LDS weights, no packed buffer (loads address the
// original tensors; read-only -> sK$/L2 resident forever). Acts/h exchange
// unchanged (LLC bypass + fused drains); fence-free relaxed barrier unchanged.
// FMA order bit-identical to R4/R5/R6b.

#define H_ 256
#define B_ 64
#define T_ 1024
#define NBLK 256
#define NTHR 1024
#define HBUF 98304     // floats per h ring buffer: 6 cells * 16384
#define NTICK 1026

// ws byte offsets
#define OFF_GEN  0
#define OFF_ROOT 64
#define OFF_CNT  128          // 8 counters, 64B apart
#define OFF_H    4096         // hbuf[2][6][16384] floats = 786432 B
#define OFF_XT   1048576      // xT2[1024][16][64][4] floats = 16 MB
#define OFF_YS   17825792     // ys[1024][64][256] floats = 64 MB

typedef __attribute__((ext_vector_type(4))) int si4;

__device__ __forceinline__ float sigf(float x) {
  return 1.0f / (1.0f + __expf(-x));
}
__device__ __forceinline__ float tanhf_(float x) {
  float e = __expf(-2.0f * fabsf(x));
  float r = (1.0f - e) / (1.0f + e);
  return x >= 0.0f ? r : -r;
}

// ---- LLC-coherent (bypass L1/L2) access helpers (R5-proven) ----
__device__ __forceinline__ void llc_ld1(const float4* p, float4& r) {
  asm volatile(
      "global_load_dwordx4 %0, %1, off sc0 sc1\n\t"
      "s_waitcnt vmcnt(0)"
      : "=v"(r)
      : "v"(p)
      : "memory");
}
__device__ __forceinline__ void llc_ld4(const float4* p, float4& r0, float4& r1,
                                        float4& r2, float4& r3) {
  asm volatile(
      "global_load_dwordx4 %0, %4, off sc0 sc1\n\t"
      "global_load_dwordx4 %1, %4, off offset:1024 sc0 sc1\n\t"
      "global_load_dwordx4 %2, %4, off offset:2048 sc0 sc1\n\t"
      "global_load_dwordx4 %3, %4, off offset:3072 sc0 sc1\n\t"
      "s_waitcnt vmcnt(0)"
      : "=&v"(r0), "=&v"(r1), "=&v"(r2), "=&v"(r3)
      : "v"(p)
      : "memory");
}
__device__ __forceinline__ void llc_st1(float* p, float v) {
  asm volatile(
      "global_store_dword %0, %1, off sc0 sc1\n\t"
      "s_waitcnt vmcnt(0)" ::"v"(p),
      "v"(v)
      : "memory");
}
__device__ __forceinline__ void llc_st2(float* p1, float v1, float* p2, float v2) {
  asm volatile(
      "global_store_dword %0, %1, off sc0 sc1\n\t"
      "global_store_dword %2, %3, off sc0 sc1\n\t"
      "s_waitcnt vmcnt(0)" ::"v"(p1),
      "v"(v1), "v"(p2), "v"(v2)
      : "memory");
}

// ---- scalar weight fetch: 8 rows x 16B for one k4, fused issue+wait ----
// off = segment-local k4 * 16 (bytes). Results in SGPRs (wave-uniform).
__device__ __forceinline__ void sload_w8(
    const float* p0, const float* p1, const float* p2, const float* p3,
    const float* p4, const float* p5, const float* p6, const float* p7,
    int off, si4& w0, si4& w1, si4& w2, si4& w3, si4& w4, si4& w5, si4& w6,
    si4& w7) {
  asm volatile(
      "s_load_dwordx4 %0, %8, %16\n\t"
      "s_load_dwordx4 %1, %9, %16\n\t"
      "s_load_dwordx4 %2, %10, %16\n\t"
      "s_load_dwordx4 %3, %11, %16\n\t"
      "s_load_dwordx4 %4, %12, %16\n\t"
      "s_load_dwordx4 %5, %13, %16\n\t"
      "s_load_dwordx4 %6, %14, %16\n\t"
      "s_load_dwordx4 %7, %15, %16\n\t"
      "s_waitcnt lgkmcnt(0)"
      : "=&s"(w0), "=&s"(w1), "=&s"(w2), "=&s"(w3), "=&s"(w4), "=&s"(w5),
        "=&s"(w6), "=&s"(w7)
      : "s"(p0), "s"(p1), "s"(p2), "s"(p3), "s"(p4), "s"(p5), "s"(p6), "s"(p7),
        "s"(off)
      : "memory");
}

// ---------------- x transpose: x[b][k][t] -> xT2[t][k>>2][b][k&3] ----------------
__global__ __launch_bounds__(64) void transpose_x(const float* __restrict__ x,
                                                  float* __restrict__ xT) {
  __shared__ float tile[64][65];
  const int k = blockIdx.y;
  const int t0 = blockIdx.x * 64;
  const int lane = threadIdx.x;
  for (int bi = 0; bi < 64; ++bi)
    tile[bi][lane] = x[bi * 65536 + k * 1024 + t0 + lane];
  __syncthreads();
  for (int ti = 0; ti < 64; ++ti)
    xT[(size_t)(t0 + ti) * 4096 + (k >> 2) * 256 + lane * 4 + (k & 3)] =
        tile[lane][ti];
}

// 8-row FMA for one k4; weights from SGPRs. Chain order == R4/R5/R6b bitwise.
#define BODY8S(av, w0, w1, w2, w3, w4, w5, w6, w7)                             \
  do {                                                                         \
    acc[0] += __int_as_float((w0).x) * (av).x + __int_as_float((w0).y) * (av).y \
            + __int_as_float((w0).z) * (av).z + __int_as_float((w0).w) * (av).w; \
    acc[1] += __int_as_float((w1).x) * (av).x + __int_as_float((w1).y) * (av).y \
            + __int_as_float((w1).z) * (av).z + __int_as_float((w1).w) * (av).w; \
    acc[2] += __int_as_float((w2).x) * (av).x + __int_as_float((w2).y) * (av).y \
            + __int_as_float((w2).z) * (av).z + __int_as_float((w2).w) * (av).w; \
    acc[3] += __int_as_float((w3).x) * (av).x + __int_as_float((w3).y) * (av).y \
            + __int_as_float((w3).z) * (av).z + __int_as_float((w3).w) * (av).w; \
    acc[4] += __int_as_float((w4).x) * (av).x + __int_as_float((w4).y) * (av).y \
            + __int_as_float((w4).z) * (av).z + __int_as_float((w4).w) * (av).w; \
    acc[5] += __int_as_float((w5).x) * (av).x + __int_as_float((w5).y) * (av).y \
            + __int_as_float((w5).z) * (av).z + __int_as_float((w5).w) * (av).w; \
    acc[6] += __int_as_float((w6).x) * (av).x + __int_as_float((w6).y) * (av).y \
            + __int_as_float((w6).z) * (av).z + __int_as_float((w6).w) * (av).w; \
    acc[7] += __int_as_float((w7).x) * (av).x + __int_as_float((w7).y) * (av).y \
            + __int_as_float((w7).z) * (av).z + __int_as_float((w7).w) * (av).w; \
  } while (0)

// segment driver: k4 ascending, batches of 4 then tail (fp order == R4..R6b).
// act indexed by (k4-actOff); weight col = (k4-actOff); weights from global
// tensor wb with row stride ws_ (floats), rows (a&3)*256+u0+(a>>2).
__device__ __forceinline__ void seg8(float* __restrict__ acc, const int a,
                                     const int b, const float4* __restrict__ act,
                                     const int actOff,
                                     const float* __restrict__ wb, const int ws_,
                                     const int u0, const int lane,
                                     const bool byp) {
  const float* p0 = wb + (size_t)(0 * 256 + u0) * ws_;
  const float* p1 = wb + (size_t)(1 * 256 + u0) * ws_;
  const float* p2 = wb + (size_t)(2 * 256 + u0) * ws_;
  const float* p3 = wb + (size_t)(3 * 256 + u0) * ws_;
  const float* p4 = wb + (size_t)(0 * 256 + u0 + 1) * ws_;
  const float* p5 = wb + (size_t)(1 * 256 + u0 + 1) * ws_;
  const float* p6 = wb + (size_t)(2 * 256 + u0 + 1) * ws_;
  const float* p7 = wb + (size_t)(3 * 256 + u0 + 1) * ws_;
  int k4 = a;
  for (; k4 + 4 <= b; k4 += 4) {
    const int kk = k4 - actOff;
    const float4* p = act + (size_t)kk * 64 + lane;
    float4 v0, v1, v2, v3;
    if (byp) {
      llc_ld4(p, v0, v1, v2, v3);
    } else {
      v0 = p[0];
      v1 = p[64];
      v2 = p[128];
      v3 = p[192];
    }
    si4 w0, w1, w2, w3, w4, w5, w6, w7;
    sload_w8(p0, p1, p2, p3, p4, p5, p6, p7, kk * 16, w0, w1, w2, w3, w4, w5,
             w6, w7);
    BODY8S(v0, w0, w1, w2, w3, w4, w5, w6, w7);
    sload_w8(p0, p1, p2, p3, p4, p5, p6, p7, kk * 16 + 16, w0, w1, w2, w3, w4,
             w5, w6, w7);
    BODY8S(v1, w0, w1, w2, w3, w4, w5, w6, w7);
    sload_w8(p0, p1, p2, p3, p4, p5, p6, p7, kk * 16 + 32, w0, w1, w2, w3, w4,
             w5, w6, w7);
    BODY8S(v2, w0, w1, w2, w3, w4, w5, w6, w7);
    sload_w8(p0, p1, p2, p3, p4, p5, p6, p7, kk * 16 + 48, w0, w1, w2, w3, w4,
             w5, w6, w7);
    BODY8S(v3, w0, w1, w2, w3, w4, w5, w6, w7);
  }
  for (; k4 < b; ++k4) {
    const int kk = k4 - actOff;
    const float4* p = act + (size_t)kk * 64 + lane;
    float4 v;
    if (byp)
      llc_ld1(p, v);
    else
      v = *p;
    si4 w0, w1, w2, w3, w4, w5, w6, w7;
    sload_w8(p0, p1, p2, p3, p4, p5, p6, p7, kk * 16, w0, w1, w2, w3, w4, w5,
             w6, w7);
    BODY8S(v, w0, w1, w2, w3, w4, w5, w6, w7);
  }
}

// ---------------- one gate task: 8 rows (2 units x 4 gates), K4 k4-groups ----
__device__ __forceinline__ void task8(
    const int w, const int lane, const int tid, const int u0,
    const int K4, const int nA4,
    const float4* __restrict__ actA, const bool bypA,  // k4 in [0, nA4)
    const float4* __restrict__ actB, const bool bypB,  // k4 in [nA4, K4)
    const float* __restrict__ wAb, const int wAs,      // seg A weights
    const float* __restrict__ wBb, const int wBs,      // seg B weights
    const float* __restrict__ bias,    // bias[g*256 + u]
    float* __restrict__ cst2,          // LDS [2][64]
    float* __restrict__ hcell,         // h write base for this cell (LLC)
    float* __restrict__ ysrow,         // ys + t*16384 or nullptr (LLC)
    float (*red)[64][12], const bool lastTask) {
  const int slice = K4 >> 4;           // K4/16 waves
  const int lo = w * slice, hi = lo + slice;
  float acc[8] = {0.f, 0.f, 0.f, 0.f, 0.f, 0.f, 0.f, 0.f};

  // segment A: k4 in [lo, min(hi,nA4))
  {
    const int b4 = hi < nA4 ? hi : nA4;
    if (lo < b4) seg8(acc, lo, b4, actA, 0, wAb, wAs, u0, lane, bypA);
  }
  // segment B: k4 in [max(lo,nA4), hi)
  {
    const int a4 = lo > nA4 ? lo : nA4;
    if (a4 < hi) seg8(acc, a4, hi, actB, nA4, wBb, wBs, u0, lane, bypB);
  }

  // 8 partials -> 2x b128 LDS writes
  *(float4*)&red[w][lane][0] = make_float4(acc[0], acc[1], acc[2], acc[3]);
  *(float4*)&red[w][lane][4] = make_float4(acc[4], acc[5], acc[6], acc[7]);
  __syncthreads();

  if (tid < 128) {
    const int uu = tid >> 6, b = tid & 63;
    // bias FIRST, then wave partials ascending (bit-identical to R2/R4/R5/R6b)
    float gi = bias[0 * 256 + u0 + uu];
    float gf = bias[1 * 256 + u0 + uu];
    float gg = bias[2 * 256 + u0 + uu];
    float go = bias[3 * 256 + u0 + uu];
#pragma unroll
    for (int ww = 0; ww < 16; ++ww) {
      float4 s = *(const float4*)&red[ww][b][uu * 4];
      gi += s.x; gf += s.y; gg += s.z; go += s.w;
    }
    float iv = sigf(gi), fv = sigf(gf), gv = tanhf_(gg), ov = sigf(go);
    float c = fv * cst2[uu * 64 + b] + iv * gv;
    cst2[uu * 64 + b] = c;
    float h = ov * tanhf_(c);
    const int u = u0 + uu;
    float* hp = hcell + (u >> 2) * 256 + b * 4 + (u & 3);
    if (ysrow)
      llc_st2(hp, h, ysrow + b * 256 + u, h);
    else
      llc_st1(hp, h);
  }
  if (!lastTask) __syncthreads();
}

// ---------------- persistent skewed LSTM ----------------
__global__ __launch_bounds__(NTHR, 1) void lstm_persistent(
    const float* __restrict__ Wih0, const float* __restrict__ Whh0,
    const float* __restrict__ b0, const float* __restrict__ Wih12,
    const float* __restrict__ Whh12, const float* __restrict__ b12, char* wsb) {
  unsigned* gen = (unsigned*)(wsb + OFF_GEN);
  unsigned* root = (unsigned*)(wsb + OFF_ROOT);
  float* hb = (float*)(wsb + OFF_H);
  const float* xT = (const float*)(wsb + OFF_XT);
  float* ys = (float*)(wsb + OFF_YS);

  __shared__ float red[16][64][12];   // 48 KB
  __shared__ float cst[3][2][64];     // per-layer c state (1.5 KB)

  const int bid = blockIdx.x;
  const int tid = threadIdx.x;
  const int lane = tid & 63;
  const int w = __builtin_amdgcn_readfirstlane(tid >> 6);  // uniform wave id
  const int d = bid >> 7;          // direction 0/1
  const int u0 = (bid & 127) * 2;  // unit tile base

  if (tid < 384) ((float*)cst)[tid] = 0.f;
  __syncthreads();

  unsigned* mycnt = (unsigned*)(wsb + OFF_CNT + (size_t)(bid & 7) * 64);

  for (unsigned tick = 0; tick < NTICK; ++tick) {
    const float* R = hb + ((tick + 1) & 1) * HBUF;  // produced last tick
    float* W = hb + (tick & 1) * HBUF;              // produced this tick
    const float4* Rf4 = (const float4*)R;

    const bool has0 = tick < 1024;
    const bool has1 = tick >= 1 && tick < 1025;
    const bool has2 = tick >= 2;

    // Layer 0 (cell d): t = tick; K4 = 16 (x, cached) + 64 (rec h, LLC)
    if (has0) {
      task8(w, lane, tid, u0, 80, 16,
            (const float4*)xT + (size_t)tick * 1024, false,
            Rf4 + (size_t)d * 4096, true,
            Wih0 + (size_t)d * 65536, 64,
            Whh0 + (size_t)d * 262144, 256,
            b0 + d * 1024, &cst[0][0][0],
            W + (size_t)d * 16384, nullptr, red, !(has1 || has2));
    }
    // Layer 1 (cell 2+d): t = tick-1; K4 = 128 (cells 0,1) + 64 (rec)
    if (has1) {
      task8(w, lane, tid, u0, 192, 128,
            Rf4, true,
            Rf4 + (size_t)(2 + d) * 4096, true,
            Wih12 + (size_t)d * 524288, 512,
            Whh12 + (size_t)d * 262144, 256,
            b12 + d * 1024, &cst[1][0][0],
            W + (size_t)(2 + d) * 16384, nullptr, red, !has2);
    }
    // Layer 2 (cell 4+d): t = tick-2; K4 = 128 (cells 2,3) + 64 (rec)
    if (has2) {
      const int t = (int)tick - 2;
      task8(w, lane, tid, u0, 192, 128,
            Rf4 + (size_t)2 * 4096, true,
            Rf4 + (size_t)(4 + d) * 4096, true,
            Wih12 + (size_t)(2 + d) * 524288, 512,
            Whh12 + (size_t)(2 + d) * 262144, 256,
            b12 + (2 + d) * 1024, &cst[2][0][0],
            W + (size_t)(4 + d) * 16384,
            (d == 1) ? (ys + (size_t)t * 16384) : nullptr, red, true);
    }

    // -------- grid barrier: pure relaxed LLC atomics, NO fences --------
    __syncthreads();
    if (tid == 0) {
      unsigned old = __hip_atomic_fetch_add(mycnt, 1u, __ATOMIC_RELAXED,
                                            __HIP_MEMORY_SCOPE_AGENT);
      if (old == (tick + 1) * (NBLK / 8) - 1) {
        unsigned r = __hip_atomic_fetch_add(root, 1u, __ATOMIC_RELAXED,
                                            __HIP_MEMORY_SCOPE_AGENT);
        if (r == (tick + 1) * 8 - 1) {
          __hip_atomic_store(gen, tick + 1, __ATOMIC_RELAXED,
                             __HIP_MEMORY_SCOPE_AGENT);
        }
      }
      while (__hip_atomic_load(gen, __ATOMIC_RELAXED, __HIP_MEMORY_SCOPE_AGENT) <
             tick + 1) {
        __builtin_amdgcn_s_sleep(2);
      }
    }
    __syncthreads();
  }
}

// ---------------- conv(256->81) + argmax ----------------
__global__ __launch_bounds__(256) void conv_argmax(const float* __restrict__ yst,
                                                   const float* __restrict__ cw,
                                                   const float* __restrict__ cb,
                                                   int* __restrict__ out) {
  const int t = blockIdx.x;
  const int tid = threadIdx.x, lane = tid & 63, w = tid >> 6;
  const float* yrow = yst + (size_t)t * (B_ * H_) + lane * H_;
  float best = -3.4e38f;
  int bi = 0;
  for (int og = 0; og < 3; ++og) {
    float acc[8];
    int ov[8];
#pragma unroll
    for (int m = 0; m < 8; ++m) {
      int o = w + 32 * og + 4 * m;
      ov[m] = (o < 81) ? o : 80;
      acc[m] = (o < 81) ? cb[o] : -3.4e38f;
    }
    for (int uu = 0; uu < H_; uu += 4) {
      float4 y4 = *(const float4*)(yrow + uu);
#pragma unroll
      for (int m = 0; m < 8; ++m) {
        const float* wr = cw + ov[m] * H_ + uu;
        acc[m] += wr[0] * y4.x + wr[1] * y4.y + wr[2] * y4.z + wr[3] * y4.w;
      }
    }
#pragma unroll
    for (int m = 0; m < 8; ++m) {
      int o = w + 32 * og + 4 * m;
      if (o < 81 && acc[m] > best) {
        best = acc[m];
        bi = o;
      }
    }
  }
  __shared__ float sv[4][64];
  __shared__ int si[4][64];
  sv[w][lane] = best;
  si[w][lane] = bi;
  __syncthreads();
  if (tid < 64) {
    float bv = sv[0][tid];
    int bo = si[0][tid];
#pragma unroll
    for (int ww = 1; ww < 4; ++ww) {
      float v = sv[ww][tid];
      int o = si[ww][tid];
      if (v > bv || (v == bv && o < bo)) {
        bv = v;
        bo = o;
      }
    }
    out[tid * T_ + t] = bo;
  }
}

extern "C" void kernel_launch(void* const* d_in, const int* in_sizes, int n_in,
                              void* d_out, int out_size, void* d_ws,
                              size_t ws_size, hipStream_t stream) {
  const float* x = (const float*)d_in[0];
  const float* Wih0 = (const float*)d_in[1];
  const float* Whh0 = (const float*)d_in[2];
  const float* b0 = (const float*)d_in[3];
  const float* Wih12 = (const float*)d_in[4];
  const float* Whh12 = (const float*)d_in[5];
  const float* b12 = (const float*)d_in[6];
  const float* cw = (const float*)d_in[7];
  const float* cb = (const float*)d_in[8];
  int* out = (int*)d_out;
  char* wsb = (char*)d_ws;

  // zero flags + h ring (ws is re-poisoned 0xAA before every launch)
  hipMemsetAsync(wsb, 0, OFF_H + 786432, stream);
  transpose_x<<<dim3(16, 64, 1), dim3(64, 1, 1), 0, stream>>>(
      x, (float*)(wsb + OFF_XT));
  lstm_persistent<<<dim3(NBLK, 1, 1), dim3(NTHR, 1, 1), 0, stream>>>(
      Wih0, Whh0, b0, Wih12, Whh12, b12, wsb);
  conv_argmax<<<dim3(T_, 1, 1), dim3(256, 1, 1), 0, stream>>>(
      (const float*)(wsb + OFF_YS), cw, cb, out);
}